// Round 6
// baseline (75.965 us; speedup 1.0000x reference)
//
#include <hip/hip_runtime.h>
#include <stdint.h>

#define MAXL 256  // L = 200 at this problem size

typedef float f4 __attribute__((ext_vector_type(4)));

#define SRC_ZERO 0xFFu   // row is all-zeros
#define SRC_MASK 0xFEu   // row is mask_emb

__device__ __forceinline__ uint32_t rotl32(uint32_t x, uint32_t d){
  return (x << d) | (x >> (32u - d));
}

// JAX threefry2x32 block (20 rounds), partitionable mode.
__device__ __forceinline__ void tf2x32(uint32_t k0, uint32_t k1,
                                       uint32_t x0, uint32_t x1,
                                       uint32_t& o0, uint32_t& o1){
  const uint32_t k2 = k0 ^ k1 ^ 0x1BD11BDAu;
  x0 += k0; x1 += k1;
  x0 += x1; x1 = rotl32(x1,13); x1 ^= x0;
  x0 += x1; x1 = rotl32(x1,15); x1 ^= x0;
  x0 += x1; x1 = rotl32(x1,26); x1 ^= x0;
  x0 += x1; x1 = rotl32(x1, 6); x1 ^= x0;
  x0 += k1; x1 += k2 + 1u;
  x0 += x1; x1 = rotl32(x1,17); x1 ^= x0;
  x0 += x1; x1 = rotl32(x1,29); x1 ^= x0;
  x0 += x1; x1 = rotl32(x1,16); x1 ^= x0;
  x0 += x1; x1 = rotl32(x1,24); x1 ^= x0;
  x0 += k2; x1 += k0 + 2u;
  x0 += x1; x1 = rotl32(x1,13); x1 ^= x0;
  x0 += x1; x1 = rotl32(x1,15); x1 ^= x0;
  x0 += x1; x1 = rotl32(x1,26); x1 ^= x0;
  x0 += x1; x1 = rotl32(x1, 6); x1 ^= x0;
  x0 += k0; x1 += k1 + 3u;
  x0 += x1; x1 = rotl32(x1,17); x1 ^= x0;
  x0 += x1; x1 = rotl32(x1,29); x1 ^= x0;
  x0 += x1; x1 = rotl32(x1,16); x1 ^= x0;
  x0 += x1; x1 = rotl32(x1,24); x1 ^= x0;
  x0 += k1; x1 += k2 + 4u;
  x0 += x1; x1 = rotl32(x1,13); x1 ^= x0;
  x0 += x1; x1 = rotl32(x1,15); x1 ^= x0;
  x0 += x1; x1 = rotl32(x1,26); x1 ^= x0;
  x0 += x1; x1 = rotl32(x1, 6); x1 ^= x0;
  x0 += k2; x1 += k0 + 5u;
  o0 = x0; o1 = x1;
}

__device__ __forceinline__ float u01(uint32_t bits){
  return __uint_as_float((bits >> 9) | 0x3F800000u) - 1.0f;
}

__device__ __forceinline__ uint32_t randint_comb(uint32_t hb, uint32_t lb, uint32_t span){
  uint32_t mult = 65536u % span;   // 2^16 % span
  mult = (mult * mult) % span;     // 2^32 % span
  return ((hb % span) * mult + (lb % span)) % span;
}

// ---------------- Kernel A: per-sequence params + uint8 source table ----------------
// d_src8[b*L+p] = sequence-relative source row (0..L-1 <= 253),
// or SRC_ZERO (0xFF) / SRC_MASK (0xFE). Per-row PRNG only for the taken branch.
__global__ __launch_bounds__(256)
void params_kernel(const int* __restrict__ slen_arr, unsigned char* __restrict__ d_src8,
                   float* __restrict__ out_tail, int B, int L)
{
  const int b    = blockIdx.x;
  const int tid  = threadIdx.x;
  const int base = b * L;

  __shared__ int   s_params[4];        // aug_type, crop_len, start_c, start_r
  __shared__ float s_rand[MAXL];       // reorder sort keys (window-relative)

  const int slen = slen_arr[b];

  // per-seq key (cheap, redundant per thread)
  uint32_t kb0, kb1;
  tf2x32(0u, 42u, 0u, (uint32_t)b, kb0, kb1);   // split(key(42),B)[b]

  // wave 0: lane-parallel randint chain. Lane p (p<6): param=p>>1, word j=p&1.
  if (tid < 64){
    uint32_t param = (uint32_t)(tid >> 1);
    uint32_t j     = (uint32_t)(tid & 1);
    uint32_t w0,w1,s0,s1,r0,r1;
    tf2x32(kb0, kb1, 0u, param, w0, w1);   // split(key_b,5)[param]
    tf2x32(w0, w1, 0u, j, s0, s1);         // split(k_param,2)[j]
    tf2x32(s0, s1, 0u, 0u, r0, r1);        // random_bits scalar
    uint32_t bits = r0 ^ r1;
    uint32_t hb_a = __shfl(bits, 0), lb_a = __shfl(bits, 1);
    uint32_t hb_c = __shfl(bits, 2), lb_c = __shfl(bits, 3);
    uint32_t hb_r = __shfl(bits, 4), lb_r = __shfl(bits, 5);
    if (tid == 0){
      int aug_type = (int)randint_comb(hb_a, lb_a, 3u);
      int crop_len = (int)(0.6f * (float)slen);      // f32 mul + trunc, as in JAX
      if (crop_len < 1) crop_len = 1;
      int span = slen - crop_len; if (span < 0) span = 0;   // re_len == crop_len
      int start_c = (int)randint_comb(hb_c, lb_c, (uint32_t)(span + 1));
      int start_r = (int)randint_comb(hb_r, lb_r, (uint32_t)(span + 1));
      s_params[0] = aug_type; s_params[1] = crop_len;
      s_params[2] = start_c;  s_params[3] = start_r;
      out_tail[b] = (float)((aug_type == 0) ? crop_len : slen);
    }
  }
  __syncthreads();

  const int aug_type = s_params[0];
  const int crop_len = s_params[1];   // == re_len
  const int start_c  = s_params[2];
  const int start_r  = s_params[3];

  if (aug_type == 0){
    // crop: pure arithmetic, no per-row PRNG
    if (tid < L)
      d_src8[base + tid] = (unsigned char)((tid < crop_len) ? (tid + start_c) : SRC_ZERO);
  } else if (aug_type == 2){
    // mask: per-row uniform only
    if (tid < L){
      uint32_t c0,c1,m0,m1;
      tf2x32(kb0, kb1, 0u, 4u, c0, c1);                 // k_mask
      tf2x32(c0, c1, 0u, (uint32_t)tid, m0, m1);
      int mflag = (u01(m0 ^ m1) < 0.3f) ? 1 : 0;
      d_src8[base + tid] = (unsigned char)((tid >= slen) ? SRC_ZERO
                                                         : (mflag ? SRC_MASK : tid));
    }
  } else {
    // reorder: keys only for the window, then stable-rank scatter (direct to global)
    const int re_len = crop_len;
    if (tid < re_len){
      uint32_t a0,a1,r0,r1;
      tf2x32(kb0, kb1, 0u, 3u, a0, a1);                 // k_reo_perm
      tf2x32(a0, a1, 0u, (uint32_t)(start_r + tid), r0, r1);
      s_rand[tid] = u01(r0 ^ r1);
    }
    // non-window rows: direct
    if (tid < L){
      bool inwin = (tid >= start_r) && (tid < start_r + re_len);
      if (!inwin) d_src8[base + tid] = (unsigned char)((tid < slen) ? tid : SRC_ZERO);
    }
    __syncthreads();   // keys visible (block-uniform branch -> legal)
    if (tid < re_len){
      float kt = s_rand[tid];
      int rank = 0;
      for (int s = 0; s < re_len; ++s){
        float ks = s_rand[s];                            // broadcast read
        rank += (int)((ks < kt) || (ks == kt && s < tid));  // stable tie-break
      }
      d_src8[base + start_r + rank] = (unsigned char)(start_r + tid);  // order[rank]=idx
    }
  }
}

// ---------------- Kernel B: pure gather/scatter streamer ----------------
// D == 64: 16 float4 per row, 16 rows per 256-thread block. NT loads+stores
// on the bulk streams (zero reuse). LT compile-time -> magic-multiply division.
template<int LT>
__global__ __launch_bounds__(256)
void scatter_kernel_d64(const f4* __restrict__ seq4, const f4* __restrict__ memb4,
                        const unsigned char* __restrict__ d_src8, f4* __restrict__ out4,
                        int n_rows)
{
  const int t   = blockIdx.x * 256 + threadIdx.x;
  const int row = t >> 4;
  const int f   = t & 15;
  if (row >= n_rows) return;
  const unsigned int src = d_src8[row];   // seq-relative, L2-hot (800 KB)
  const int seqb = (row / LT) * LT;       // LT constant -> mulhi, no div
  f4 v = {0.f, 0.f, 0.f, 0.f};
  if (src < SRC_MASK)
    v = __builtin_nontemporal_load(&seq4[(size_t)(seqb + (int)src) * 16 + f]);
  else if (src == SRC_MASK)
    v = memb4[f];                         // 256B total, cache-hot
  __builtin_nontemporal_store(v, &out4[(size_t)row * 16 + f]);
}

// generic fallback (runtime L <= 253, runtime f_per_row)
__global__ __launch_bounds__(256)
void scatter_kernel_gen(const f4* __restrict__ seq4, const f4* __restrict__ memb4,
                        const unsigned char* __restrict__ d_src8, f4* __restrict__ out4,
                        int n_rows, int f_per_row, int L)
{
  const int t = blockIdx.x * 256 + threadIdx.x;
  const int row = t / f_per_row;
  const int f   = t - row * f_per_row;
  if (row >= n_rows) return;
  const unsigned int src = d_src8[row];
  const int seqb = (row / L) * L;
  f4 v = {0.f, 0.f, 0.f, 0.f};
  if (src < SRC_MASK)
    v = __builtin_nontemporal_load(&seq4[(size_t)(seqb + (int)src) * f_per_row + f]);
  else if (src == SRC_MASK)
    v = memb4[f];
  __builtin_nontemporal_store(v, &out4[(size_t)row * f_per_row + f]);
}

extern "C" void kernel_launch(void* const* d_in, const int* in_sizes, int n_in,
                              void* d_out, int out_size, void* d_ws, size_t ws_size,
                              hipStream_t stream) {
  const float* seq  = (const float*)d_in[0];
  const int*   slen = (const int*)  d_in[1];
  const float* memb = (const float*)d_in[2];
  float*       out  = (float*)d_out;
  const int B = in_sizes[1];
  const int D = in_sizes[2];
  const int L = in_sizes[0] / (B * D);

  unsigned char* d_src8 = (unsigned char*)d_ws;   // B*L bytes (800 KB) in workspace

  hipLaunchKernelGGL(params_kernel, dim3(B), dim3(256), 0, stream,
                     slen, d_src8, out + (size_t)B * L * D, B, L);

  const int n_rows = B * L;
  const int fpr = D >> 2;
  const long total4 = (long)n_rows * fpr;
  const int grid = (int)((total4 + 255) / 256);
  if (fpr == 16 && L == 200){
    hipLaunchKernelGGL((scatter_kernel_d64<200>), dim3(grid), dim3(256), 0, stream,
                       (const f4*)seq, (const f4*)memb, d_src8, (f4*)out, n_rows);
  } else {
    hipLaunchKernelGGL(scatter_kernel_gen, dim3(grid), dim3(256), 0, stream,
                       (const f4*)seq, (const f4*)memb, d_src8, (f4*)out, n_rows, fpr, L);
  }
}

// Round 7
// 68.060 us; speedup vs baseline: 1.1161x; 1.1161x over previous
//
#include <hip/hip_runtime.h>
#include <stdint.h>

#define MAXL 256  // L = 200 at this problem size

typedef float f4 __attribute__((ext_vector_type(4)));

__device__ __forceinline__ uint32_t rotl32(uint32_t x, uint32_t d){
  return (x << d) | (x >> (32u - d));
}

// JAX threefry2x32 block (20 rounds), partitionable mode.
__device__ __forceinline__ void tf2x32(uint32_t k0, uint32_t k1,
                                       uint32_t x0, uint32_t x1,
                                       uint32_t& o0, uint32_t& o1){
  const uint32_t k2 = k0 ^ k1 ^ 0x1BD11BDAu;
  x0 += k0; x1 += k1;
  x0 += x1; x1 = rotl32(x1,13); x1 ^= x0;
  x0 += x1; x1 = rotl32(x1,15); x1 ^= x0;
  x0 += x1; x1 = rotl32(x1,26); x1 ^= x0;
  x0 += x1; x1 = rotl32(x1, 6); x1 ^= x0;
  x0 += k1; x1 += k2 + 1u;
  x0 += x1; x1 = rotl32(x1,17); x1 ^= x0;
  x0 += x1; x1 = rotl32(x1,29); x1 ^= x0;
  x0 += x1; x1 = rotl32(x1,16); x1 ^= x0;
  x0 += x1; x1 = rotl32(x1,24); x1 ^= x0;
  x0 += k2; x1 += k0 + 2u;
  x0 += x1; x1 = rotl32(x1,13); x1 ^= x0;
  x0 += x1; x1 = rotl32(x1,15); x1 ^= x0;
  x0 += x1; x1 = rotl32(x1,26); x1 ^= x0;
  x0 += x1; x1 = rotl32(x1, 6); x1 ^= x0;
  x0 += k0; x1 += k1 + 3u;
  x0 += x1; x1 = rotl32(x1,17); x1 ^= x0;
  x0 += x1; x1 = rotl32(x1,29); x1 ^= x0;
  x0 += x1; x1 = rotl32(x1,16); x1 ^= x0;
  x0 += x1; x1 = rotl32(x1,24); x1 ^= x0;
  x0 += k1; x1 += k2 + 4u;
  x0 += x1; x1 = rotl32(x1,13); x1 ^= x0;
  x0 += x1; x1 = rotl32(x1,15); x1 ^= x0;
  x0 += x1; x1 = rotl32(x1,26); x1 ^= x0;
  x0 += x1; x1 = rotl32(x1, 6); x1 ^= x0;
  x0 += k2; x1 += k0 + 5u;
  o0 = x0; o1 = x1;
}

__device__ __forceinline__ float u01(uint32_t bits){
  return __uint_as_float((bits >> 9) | 0x3F800000u) - 1.0f;
}

__device__ __forceinline__ uint32_t randint_comb(uint32_t hb, uint32_t lb, uint32_t span){
  uint32_t mult = 65536u % span;   // 2^16 % span
  mult = (mult * mult) % span;     // 2^32 % span
  return ((hb % span) * mult + (lb % span)) % span;
}

// ---------------- Kernel A: per-sequence params + int32 source table ----------------
// (int8 table regressed 36% in R6 — sub-dword table ops lose; keep int32.)
// d_src[b*L+p] = absolute source row (b*L + src), or -1 (zero) / -2 (mask_emb).
// Per-row PRNG is computed ONLY for the branch the sequence actually takes.
__global__ __launch_bounds__(256)
void params_kernel(const int* __restrict__ slen_arr, int* __restrict__ d_src,
                   float* __restrict__ out_tail, int B, int L)
{
  const int b    = blockIdx.x;
  const int tid  = threadIdx.x;
  const int base = b * L;

  __shared__ int   s_params[4];        // aug_type, crop_len, start_c, start_r
  __shared__ float s_rand[MAXL];       // reorder sort keys (window-relative)

  const int slen = slen_arr[b];

  // per-seq key (cheap, redundant per thread)
  uint32_t kb0, kb1;
  tf2x32(0u, 42u, 0u, (uint32_t)b, kb0, kb1);   // split(key(42),B)[b]

  // wave 0: lane-parallel randint chain. Lane p (p<6): param=p>>1, word j=p&1.
  if (tid < 64){
    uint32_t param = (uint32_t)(tid >> 1);
    uint32_t j     = (uint32_t)(tid & 1);
    uint32_t w0,w1,s0,s1,r0,r1;
    tf2x32(kb0, kb1, 0u, param, w0, w1);   // split(key_b,5)[param]
    tf2x32(w0, w1, 0u, j, s0, s1);         // split(k_param,2)[j]
    tf2x32(s0, s1, 0u, 0u, r0, r1);        // random_bits scalar
    uint32_t bits = r0 ^ r1;
    uint32_t hb_a = __shfl(bits, 0), lb_a = __shfl(bits, 1);
    uint32_t hb_c = __shfl(bits, 2), lb_c = __shfl(bits, 3);
    uint32_t hb_r = __shfl(bits, 4), lb_r = __shfl(bits, 5);
    if (tid == 0){
      int aug_type = (int)randint_comb(hb_a, lb_a, 3u);
      int crop_len = (int)(0.6f * (float)slen);      // f32 mul + trunc, as in JAX
      if (crop_len < 1) crop_len = 1;
      int span = slen - crop_len; if (span < 0) span = 0;   // re_len == crop_len
      int start_c = (int)randint_comb(hb_c, lb_c, (uint32_t)(span + 1));
      int start_r = (int)randint_comb(hb_r, lb_r, (uint32_t)(span + 1));
      s_params[0] = aug_type; s_params[1] = crop_len;
      s_params[2] = start_c;  s_params[3] = start_r;
      out_tail[b] = (float)((aug_type == 0) ? crop_len : slen);
    }
  }
  __syncthreads();

  const int aug_type = s_params[0];
  const int crop_len = s_params[1];   // == re_len
  const int start_c  = s_params[2];
  const int start_r  = s_params[3];

  if (aug_type == 0){
    // crop: pure arithmetic, no per-row PRNG
    if (tid < L)
      d_src[base + tid] = (tid < crop_len) ? (base + tid + start_c) : -1;
  } else if (aug_type == 2){
    // mask: per-row uniform only
    if (tid < L){
      uint32_t c0,c1,m0,m1;
      tf2x32(kb0, kb1, 0u, 4u, c0, c1);                 // k_mask
      tf2x32(c0, c1, 0u, (uint32_t)tid, m0, m1);
      int mflag = (u01(m0 ^ m1) < 0.3f) ? 1 : 0;
      d_src[base + tid] = (tid >= slen) ? -1 : (mflag ? -2 : (base + tid));
    }
  } else {
    // reorder: keys only for the window, then stable-rank scatter (direct to global)
    const int re_len = crop_len;
    if (tid < re_len){
      uint32_t a0,a1,r0,r1;
      tf2x32(kb0, kb1, 0u, 3u, a0, a1);                 // k_reo_perm
      tf2x32(a0, a1, 0u, (uint32_t)(start_r + tid), r0, r1);
      s_rand[tid] = u01(r0 ^ r1);
    }
    // non-window rows: direct
    if (tid < L){
      bool inwin = (tid >= start_r) && (tid < start_r + re_len);
      if (!inwin) d_src[base + tid] = (tid < slen) ? (base + tid) : -1;
    }
    __syncthreads();   // keys visible (block-uniform branch -> legal)
    if (tid < re_len){
      float kt = s_rand[tid];
      int rank = 0;
      for (int s = 0; s < re_len; ++s){
        float ks = s_rand[s];                            // broadcast read
        rank += (int)((ks < kt) || (ks == kt && s < tid));  // stable tie-break
      }
      d_src[base + start_r + rank] = base + start_r + tid;  // order[rank]=idx
    }
  }
}

// ---------------- Kernel B: pure gather/scatter streamer ----------------
// D == 64: 32 B/thread — each thread handles two float4s of its row
// (8 threads/row). NT loads+stores on the bulk streams (zero reuse).
__global__ __launch_bounds__(256)
void scatter_kernel_d64(const f4* __restrict__ seq4, const f4* __restrict__ memb4,
                        const int* __restrict__ d_src, f4* __restrict__ out4,
                        int n_rows)
{
  const int t   = blockIdx.x * 256 + threadIdx.x;
  const int row = t >> 3;
  const int f   = t & 7;          // handles f4 indices f and f+8
  if (row >= n_rows) return;
  const int src = d_src[row];     // 3.2 MB table, L2-hot
  f4 v0 = {0.f, 0.f, 0.f, 0.f};
  f4 v1 = {0.f, 0.f, 0.f, 0.f};
  if (src >= 0){
    const f4* p = &seq4[(size_t)src * 16];
    v0 = __builtin_nontemporal_load(&p[f]);
    v1 = __builtin_nontemporal_load(&p[f + 8]);
  } else if (src == -2){
    v0 = memb4[f];                // 256 B total, cache-hot
    v1 = memb4[f + 8];
  }
  f4* q = &out4[(size_t)row * 16];
  __builtin_nontemporal_store(v0, &q[f]);
  __builtin_nontemporal_store(v1, &q[f + 8]);
}

// generic D fallback (16 B/thread)
__global__ __launch_bounds__(256)
void scatter_kernel_gen(const f4* __restrict__ seq4, const f4* __restrict__ memb4,
                        const int* __restrict__ d_src, f4* __restrict__ out4,
                        int n_rows, int f_per_row)
{
  const int t = blockIdx.x * 256 + threadIdx.x;
  const int row = t / f_per_row;
  const int f   = t - row * f_per_row;
  if (row >= n_rows) return;
  const int src = d_src[row];
  f4 v = {0.f, 0.f, 0.f, 0.f};
  if (src >= 0)       v = __builtin_nontemporal_load(&seq4[(size_t)src * f_per_row + f]);
  else if (src == -2) v = memb4[f];
  __builtin_nontemporal_store(v, &out4[(size_t)row * f_per_row + f]);
}

extern "C" void kernel_launch(void* const* d_in, const int* in_sizes, int n_in,
                              void* d_out, int out_size, void* d_ws, size_t ws_size,
                              hipStream_t stream) {
  const float* seq  = (const float*)d_in[0];
  const int*   slen = (const int*)  d_in[1];
  const float* memb = (const float*)d_in[2];
  float*       out  = (float*)d_out;
  const int B = in_sizes[1];
  const int D = in_sizes[2];
  const int L = in_sizes[0] / (B * D);

  int* d_src = (int*)d_ws;                 // B*L ints (3.3 MB) in workspace

  hipLaunchKernelGGL(params_kernel, dim3(B), dim3(256), 0, stream,
                     slen, d_src, out + (size_t)B * L * D, B, L);

  const int n_rows = B * L;
  const int fpr = D >> 2;
  if (fpr == 16){
    const long total = (long)n_rows * 8;   // 8 threads per row
    const int grid = (int)((total + 255) / 256);
    hipLaunchKernelGGL(scatter_kernel_d64, dim3(grid), dim3(256), 0, stream,
                       (const f4*)seq, (const f4*)memb, d_src, (f4*)out, n_rows);
  } else {
    const long total4 = (long)n_rows * fpr;
    const int grid = (int)((total4 + 255) / 256);
    hipLaunchKernelGGL(scatter_kernel_gen, dim3(grid), dim3(256), 0, stream,
                       (const f4*)seq, (const f4*)memb, d_src, (f4*)out, n_rows, fpr);
  }
}

// Round 8
// 66.573 us; speedup vs baseline: 1.1411x; 1.0223x over previous
//
#include <hip/hip_runtime.h>
#include <stdint.h>

#define MAXL 256  // L = 200 at this problem size

typedef float f4 __attribute__((ext_vector_type(4)));

__device__ __forceinline__ uint32_t rotl32(uint32_t x, uint32_t d){
  return (x << d) | (x >> (32u - d));
}

// JAX threefry2x32 block (20 rounds), partitionable mode.
__device__ __forceinline__ void tf2x32(uint32_t k0, uint32_t k1,
                                       uint32_t x0, uint32_t x1,
                                       uint32_t& o0, uint32_t& o1){
  const uint32_t k2 = k0 ^ k1 ^ 0x1BD11BDAu;
  x0 += k0; x1 += k1;
  x0 += x1; x1 = rotl32(x1,13); x1 ^= x0;
  x0 += x1; x1 = rotl32(x1,15); x1 ^= x0;
  x0 += x1; x1 = rotl32(x1,26); x1 ^= x0;
  x0 += x1; x1 = rotl32(x1, 6); x1 ^= x0;
  x0 += k1; x1 += k2 + 1u;
  x0 += x1; x1 = rotl32(x1,17); x1 ^= x0;
  x0 += x1; x1 = rotl32(x1,29); x1 ^= x0;
  x0 += x1; x1 = rotl32(x1,16); x1 ^= x0;
  x0 += x1; x1 = rotl32(x1,24); x1 ^= x0;
  x0 += k2; x1 += k0 + 2u;
  x0 += x1; x1 = rotl32(x1,13); x1 ^= x0;
  x0 += x1; x1 = rotl32(x1,15); x1 ^= x0;
  x0 += x1; x1 = rotl32(x1,26); x1 ^= x0;
  x0 += x1; x1 = rotl32(x1, 6); x1 ^= x0;
  x0 += k0; x1 += k1 + 3u;
  x0 += x1; x1 = rotl32(x1,17); x1 ^= x0;
  x0 += x1; x1 = rotl32(x1,29); x1 ^= x0;
  x0 += x1; x1 = rotl32(x1,16); x1 ^= x0;
  x0 += x1; x1 = rotl32(x1,24); x1 ^= x0;
  x0 += k1; x1 += k2 + 4u;
  x0 += x1; x1 = rotl32(x1,13); x1 ^= x0;
  x0 += x1; x1 = rotl32(x1,15); x1 ^= x0;
  x0 += x1; x1 = rotl32(x1,26); x1 ^= x0;
  x0 += x1; x1 = rotl32(x1, 6); x1 ^= x0;
  x0 += k2; x1 += k0 + 5u;
  o0 = x0; o1 = x1;
}

__device__ __forceinline__ float u01(uint32_t bits){
  return __uint_as_float((bits >> 9) | 0x3F800000u) - 1.0f;
}

__device__ __forceinline__ uint32_t randint_comb(uint32_t hb, uint32_t lb, uint32_t span){
  uint32_t mult = 65536u % span;   // 2^16 % span
  mult = (mult * mult) % span;     // 2^32 % span
  return ((hb % span) * mult + (lb % span)) % span;
}

// ---------------- Fused kernel: one block per sequence ----------------
// Phase 1: params (6-lane-parallel randint chain, branch-specialized per-row PRNG)
// building an LDS source table (no global table round-trip).
// Phase 2: R4's proven streamer: 16 threads/row, contiguous 1KB/wave NT ops.
__global__ __launch_bounds__(256)
void seqaug_fused(const float* __restrict__ seq, const int* __restrict__ slen_arr,
                  const float* __restrict__ memb, float* __restrict__ out,
                  int B, int L, int D)
{
  const int b   = blockIdx.x;
  const int tid = threadIdx.x;

  __shared__ int   s_params[4];        // aug_type, crop_len, start_c, start_r
  __shared__ float s_rand[MAXL];       // reorder sort keys (window-relative)
  __shared__ int   s_src[MAXL];        // seq-relative source row, -1 zero, -2 mask
  __shared__ f4    s_memb[64];         // mask_emb as float4

  const int slen = slen_arr[b];
  const int fpr  = D >> 2;

  // per-seq key (cheap, redundant per thread)
  uint32_t kb0, kb1;
  tf2x32(0u, 42u, 0u, (uint32_t)b, kb0, kb1);   // split(key(42),B)[b]

  // stage mask_emb (threads 64..) while wave 0 runs the randint chain
  if (tid >= 64 && tid < 64 + fpr)
    s_memb[tid - 64] = ((const f4*)memb)[tid - 64];

  // wave 0: lane-parallel randint chain. Lane p (p<6): param=p>>1, word j=p&1.
  if (tid < 64){
    uint32_t param = (uint32_t)(tid >> 1);
    uint32_t j     = (uint32_t)(tid & 1);
    uint32_t w0,w1,s0,s1,r0,r1;
    tf2x32(kb0, kb1, 0u, param, w0, w1);   // split(key_b,5)[param]
    tf2x32(w0, w1, 0u, j, s0, s1);         // split(k_param,2)[j]
    tf2x32(s0, s1, 0u, 0u, r0, r1);        // random_bits scalar
    uint32_t bits = r0 ^ r1;
    uint32_t hb_a = __shfl(bits, 0), lb_a = __shfl(bits, 1);
    uint32_t hb_c = __shfl(bits, 2), lb_c = __shfl(bits, 3);
    uint32_t hb_r = __shfl(bits, 4), lb_r = __shfl(bits, 5);
    if (tid == 0){
      int aug_type = (int)randint_comb(hb_a, lb_a, 3u);
      int crop_len = (int)(0.6f * (float)slen);      // f32 mul + trunc, as in JAX
      if (crop_len < 1) crop_len = 1;
      int span = slen - crop_len; if (span < 0) span = 0;   // re_len == crop_len
      int start_c = (int)randint_comb(hb_c, lb_c, (uint32_t)(span + 1));
      int start_r = (int)randint_comb(hb_r, lb_r, (uint32_t)(span + 1));
      s_params[0] = aug_type; s_params[1] = crop_len;
      s_params[2] = start_c;  s_params[3] = start_r;
      out[(size_t)B * L * D + b] = (float)((aug_type == 0) ? crop_len : slen);
    }
  }
  __syncthreads();

  const int aug_type = s_params[0];
  const int crop_len = s_params[1];   // == re_len
  const int start_c  = s_params[2];
  const int start_r  = s_params[3];

  // branch-specialized LDS source table (block-uniform branches)
  if (aug_type == 0){
    if (tid < L)
      s_src[tid] = (tid < crop_len) ? (tid + start_c) : -1;
  } else if (aug_type == 2){
    if (tid < L){
      uint32_t c0,c1,m0,m1;
      tf2x32(kb0, kb1, 0u, 4u, c0, c1);                 // k_mask
      tf2x32(c0, c1, 0u, (uint32_t)tid, m0, m1);
      int mflag = (u01(m0 ^ m1) < 0.3f) ? 1 : 0;
      s_src[tid] = (tid >= slen) ? -1 : (mflag ? -2 : tid);
    }
  } else {
    const int re_len = crop_len;
    if (tid < re_len){
      uint32_t a0,a1,r0,r1;
      tf2x32(kb0, kb1, 0u, 3u, a0, a1);                 // k_reo_perm
      tf2x32(a0, a1, 0u, (uint32_t)(start_r + tid), r0, r1);
      s_rand[tid] = u01(r0 ^ r1);
    }
    if (tid < L){
      bool inwin = (tid >= start_r) && (tid < start_r + re_len);
      if (!inwin) s_src[tid] = (tid < slen) ? tid : -1;
    }
    __syncthreads();   // keys visible (block-uniform branch -> legal)
    if (tid < re_len){
      float kt = s_rand[tid];
      int rank = 0;
      for (int s = 0; s < re_len; ++s){
        float ks = s_rand[s];                            // broadcast read
        rank += (int)((ks < kt) || (ks == kt && s < tid));  // stable tie-break
      }
      s_src[start_r + rank] = start_r + tid;             // order[rank]=idx
    }
  }
  __syncthreads();

  // ---- streaming phase: R4's proven pattern (16 threads/row for D=64,
  // wave footprint = 1KB contiguous), NT loads+stores.
  const f4* seq4 = (const f4*)(seq + (size_t)b * L * D);
  f4*       out4 = (f4*)(out + (size_t)b * L * D);
  const f4 zero4 = {0.f, 0.f, 0.f, 0.f};
  if (fpr == 16){
    const int total = L * 16;
    for (int idx = tid; idx < total; idx += 256){
      const int p = idx >> 4;
      const int f = idx & 15;
      const int src = s_src[p];
      f4 v;
      if (src >= 0)       v = __builtin_nontemporal_load(&seq4[src * 16 + f]);
      else if (src == -2) v = s_memb[f];
      else                v = zero4;
      __builtin_nontemporal_store(v, &out4[idx]);
    }
  } else {
    const int total = L * fpr;
    for (int idx = tid; idx < total; idx += 256){
      const int p = idx / fpr;
      const int f = idx - p * fpr;
      const int src = s_src[p];
      f4 v;
      if (src >= 0)       v = __builtin_nontemporal_load(&seq4[src * fpr + f]);
      else if (src == -2) v = s_memb[f];
      else                v = zero4;
      __builtin_nontemporal_store(v, &out4[idx]);
    }
  }
}

extern "C" void kernel_launch(void* const* d_in, const int* in_sizes, int n_in,
                              void* d_out, int out_size, void* d_ws, size_t ws_size,
                              hipStream_t stream) {
  const float* seq  = (const float*)d_in[0];
  const int*   slen = (const int*)  d_in[1];
  const float* memb = (const float*)d_in[2];
  float*       out  = (float*)d_out;
  const int B = in_sizes[1];
  const int D = in_sizes[2];
  const int L = in_sizes[0] / (B * D);

  hipLaunchKernelGGL(seqaug_fused, dim3(B), dim3(256), 0, stream,
                     seq, slen, memb, out, B, L, D);
}

// Round 9
// 55.650 us; speedup vs baseline: 1.3650x; 1.1963x over previous
//
#include <hip/hip_runtime.h>
#include <stdint.h>

#define MAXL 256  // L = 200 at this problem size

typedef float f4 __attribute__((ext_vector_type(4)));

__device__ __forceinline__ uint32_t rotl32(uint32_t x, uint32_t d){
  return (x << d) | (x >> (32u - d));
}

// JAX threefry2x32 block (20 rounds), partitionable mode.
__device__ __forceinline__ void tf2x32(uint32_t k0, uint32_t k1,
                                       uint32_t x0, uint32_t x1,
                                       uint32_t& o0, uint32_t& o1){
  const uint32_t k2 = k0 ^ k1 ^ 0x1BD11BDAu;
  x0 += k0; x1 += k1;
  x0 += x1; x1 = rotl32(x1,13); x1 ^= x0;
  x0 += x1; x1 = rotl32(x1,15); x1 ^= x0;
  x0 += x1; x1 = rotl32(x1,26); x1 ^= x0;
  x0 += x1; x1 = rotl32(x1, 6); x1 ^= x0;
  x0 += k1; x1 += k2 + 1u;
  x0 += x1; x1 = rotl32(x1,17); x1 ^= x0;
  x0 += x1; x1 = rotl32(x1,29); x1 ^= x0;
  x0 += x1; x1 = rotl32(x1,16); x1 ^= x0;
  x0 += x1; x1 = rotl32(x1,24); x1 ^= x0;
  x0 += k2; x1 += k0 + 2u;
  x0 += x1; x1 = rotl32(x1,13); x1 ^= x0;
  x0 += x1; x1 = rotl32(x1,15); x1 ^= x0;
  x0 += x1; x1 = rotl32(x1,26); x1 ^= x0;
  x0 += x1; x1 = rotl32(x1, 6); x1 ^= x0;
  x0 += k0; x1 += k1 + 3u;
  x0 += x1; x1 = rotl32(x1,17); x1 ^= x0;
  x0 += x1; x1 = rotl32(x1,29); x1 ^= x0;
  x0 += x1; x1 = rotl32(x1,16); x1 ^= x0;
  x0 += x1; x1 = rotl32(x1,24); x1 ^= x0;
  x0 += k1; x1 += k2 + 4u;
  x0 += x1; x1 = rotl32(x1,13); x1 ^= x0;
  x0 += x1; x1 = rotl32(x1,15); x1 ^= x0;
  x0 += x1; x1 = rotl32(x1,26); x1 ^= x0;
  x0 += x1; x1 = rotl32(x1, 6); x1 ^= x0;
  x0 += k2; x1 += k0 + 5u;
  o0 = x0; o1 = x1;
}

__device__ __forceinline__ float u01(uint32_t bits){
  return __uint_as_float((bits >> 9) | 0x3F800000u) - 1.0f;
}

__device__ __forceinline__ uint32_t randint_comb(uint32_t hb, uint32_t lb, uint32_t span){
  uint32_t mult = 65536u % span;   // 2^16 % span
  mult = (mult * mult) % span;     // 2^32 % span
  return ((hb % span) * mult + (lb % span)) % span;
}

// ---------------- Kernel A: per-sequence params + int32 source table ----------------
// d_src[b*L+p] = absolute source row (b*L + src), or -1 (zero) / -2 (mask_emb).
// Per-row PRNG is computed ONLY for the branch the sequence actually takes.
// (Proven optimum R4. Failed alternatives: int8 table (R6, +36%), 32B/thread B
// (R7, +22%), fused single-kernel (R2/R8, +12-20%).)
__global__ __launch_bounds__(256)
void params_kernel(const int* __restrict__ slen_arr, int* __restrict__ d_src,
                   float* __restrict__ out_tail, int B, int L)
{
  const int b    = blockIdx.x;
  const int tid  = threadIdx.x;
  const int base = b * L;

  __shared__ int   s_params[4];        // aug_type, crop_len, start_c, start_r
  __shared__ float s_rand[MAXL];       // reorder sort keys (window-relative)

  const int slen = slen_arr[b];

  // per-seq key (cheap, redundant per thread)
  uint32_t kb0, kb1;
  tf2x32(0u, 42u, 0u, (uint32_t)b, kb0, kb1);   // split(key(42),B)[b]

  // wave 0: lane-parallel randint chain. Lane p (p<6): param=p>>1, word j=p&1.
  if (tid < 64){
    uint32_t param = (uint32_t)(tid >> 1);
    uint32_t j     = (uint32_t)(tid & 1);
    uint32_t w0,w1,s0,s1,r0,r1;
    tf2x32(kb0, kb1, 0u, param, w0, w1);   // split(key_b,5)[param]
    tf2x32(w0, w1, 0u, j, s0, s1);         // split(k_param,2)[j]
    tf2x32(s0, s1, 0u, 0u, r0, r1);        // random_bits scalar
    uint32_t bits = r0 ^ r1;
    uint32_t hb_a = __shfl(bits, 0), lb_a = __shfl(bits, 1);
    uint32_t hb_c = __shfl(bits, 2), lb_c = __shfl(bits, 3);
    uint32_t hb_r = __shfl(bits, 4), lb_r = __shfl(bits, 5);
    if (tid == 0){
      int aug_type = (int)randint_comb(hb_a, lb_a, 3u);
      int crop_len = (int)(0.6f * (float)slen);      // f32 mul + trunc, as in JAX
      if (crop_len < 1) crop_len = 1;
      int span = slen - crop_len; if (span < 0) span = 0;   // re_len == crop_len
      int start_c = (int)randint_comb(hb_c, lb_c, (uint32_t)(span + 1));
      int start_r = (int)randint_comb(hb_r, lb_r, (uint32_t)(span + 1));
      s_params[0] = aug_type; s_params[1] = crop_len;
      s_params[2] = start_c;  s_params[3] = start_r;
      out_tail[b] = (float)((aug_type == 0) ? crop_len : slen);
    }
  }
  __syncthreads();

  const int aug_type = s_params[0];
  const int crop_len = s_params[1];   // == re_len
  const int start_c  = s_params[2];
  const int start_r  = s_params[3];

  if (aug_type == 0){
    // crop: pure arithmetic, no per-row PRNG
    if (tid < L)
      d_src[base + tid] = (tid < crop_len) ? (base + tid + start_c) : -1;
  } else if (aug_type == 2){
    // mask: per-row uniform only
    if (tid < L){
      uint32_t c0,c1,m0,m1;
      tf2x32(kb0, kb1, 0u, 4u, c0, c1);                 // k_mask
      tf2x32(c0, c1, 0u, (uint32_t)tid, m0, m1);
      int mflag = (u01(m0 ^ m1) < 0.3f) ? 1 : 0;
      d_src[base + tid] = (tid >= slen) ? -1 : (mflag ? -2 : (base + tid));
    }
  } else {
    // reorder: keys only for the window, then stable-rank scatter (direct to global)
    const int re_len = crop_len;
    if (tid < re_len){
      uint32_t a0,a1,r0,r1;
      tf2x32(kb0, kb1, 0u, 3u, a0, a1);                 // k_reo_perm
      tf2x32(a0, a1, 0u, (uint32_t)(start_r + tid), r0, r1);
      s_rand[tid] = u01(r0 ^ r1);
    }
    // non-window rows: direct
    if (tid < L){
      bool inwin = (tid >= start_r) && (tid < start_r + re_len);
      if (!inwin) d_src[base + tid] = (tid < slen) ? (base + tid) : -1;
    }
    __syncthreads();   // keys visible (block-uniform branch -> legal)
    if (tid < re_len){
      float kt = s_rand[tid];
      int rank = 0;
      for (int s = 0; s < re_len; ++s){
        float ks = s_rand[s];                            // broadcast read
        rank += (int)((ks < kt) || (ks == kt && s < tid));  // stable tie-break
      }
      d_src[base + start_r + rank] = base + start_r + tid;  // order[rank]=idx
    }
  }
}

// ---------------- Kernel B: pure gather/scatter streamer ----------------
// D == 64: 16 float4 per row, 16 rows per 256-thread block — each wave's
// footprint is one contiguous 1KB span (4 rows). NT loads+stores on the bulk
// streams (zero reuse). Proven optimum; do not re-split per-thread width.
__global__ __launch_bounds__(256)
void scatter_kernel_d64(const f4* __restrict__ seq4, const f4* __restrict__ memb4,
                        const int* __restrict__ d_src, f4* __restrict__ out4,
                        int n_rows)
{
  const int t   = blockIdx.x * 256 + threadIdx.x;
  const int row = t >> 4;
  const int f   = t & 15;
  if (row >= n_rows) return;
  const int src = d_src[row];     // 3.3 MB table, L2-hot
  f4 v = {0.f, 0.f, 0.f, 0.f};
  if (src >= 0)       v = __builtin_nontemporal_load(&seq4[(size_t)src * 16 + f]);
  else if (src == -2) v = memb4[f];   // 256B total, cache-hot
  __builtin_nontemporal_store(v, &out4[(size_t)row * 16 + f]);
}

// generic D fallback (16 B/thread)
__global__ __launch_bounds__(256)
void scatter_kernel_gen(const f4* __restrict__ seq4, const f4* __restrict__ memb4,
                        const int* __restrict__ d_src, f4* __restrict__ out4,
                        int n_rows, int f_per_row)
{
  const int t = blockIdx.x * 256 + threadIdx.x;
  const int row = t / f_per_row;
  const int f   = t - row * f_per_row;
  if (row >= n_rows) return;
  const int src = d_src[row];
  f4 v = {0.f, 0.f, 0.f, 0.f};
  if (src >= 0)       v = __builtin_nontemporal_load(&seq4[(size_t)src * f_per_row + f]);
  else if (src == -2) v = memb4[f];
  __builtin_nontemporal_store(v, &out4[(size_t)row * f_per_row + f]);
}

extern "C" void kernel_launch(void* const* d_in, const int* in_sizes, int n_in,
                              void* d_out, int out_size, void* d_ws, size_t ws_size,
                              hipStream_t stream) {
  const float* seq  = (const float*)d_in[0];
  const int*   slen = (const int*)  d_in[1];
  const float* memb = (const float*)d_in[2];
  float*       out  = (float*)d_out;
  const int B = in_sizes[1];
  const int D = in_sizes[2];
  const int L = in_sizes[0] / (B * D);

  int* d_src = (int*)d_ws;                 // B*L ints (3.3 MB) in workspace

  hipLaunchKernelGGL(params_kernel, dim3(B), dim3(256), 0, stream,
                     slen, d_src, out + (size_t)B * L * D, B, L);

  const int n_rows = B * L;
  const int fpr = D >> 2;
  const long total4 = (long)n_rows * fpr;
  const int grid = (int)((total4 + 255) / 256);
  if (fpr == 16){
    hipLaunchKernelGGL(scatter_kernel_d64, dim3(grid), dim3(256), 0, stream,
                       (const f4*)seq, (const f4*)memb, d_src, (f4*)out, n_rows);
  } else {
    hipLaunchKernelGGL(scatter_kernel_gen, dim3(grid), dim3(256), 0, stream,
                       (const f4*)seq, (const f4*)memb, d_src, (f4*)out, n_rows, fpr);
  }
}